// Round 7
// baseline (827.186 us; speedup 1.0000x reference)
//
#include <hip/hip_runtime.h>

#define Nn 10000
#define Ee 160000
#define HID 256
#define EDIM 9
#define INDIM 10
#define Tt 5

typedef _Float16 f16;
typedef _Float16 f16x8 __attribute__((ext_vector_type(8)));
typedef _Float16 f16x4 __attribute__((ext_vector_type(4)));
typedef float f32x4 __attribute__((ext_vector_type(4)));

// ---------------- edge-attr column stats (mean / sumsq) ----------------
__global__ __launch_bounds__(256) void colstats_kernel(const float* __restrict__ in,
                                                       float* __restrict__ cs) {
  float s[9], s2[9];
#pragma unroll
  for (int k = 0; k < 9; ++k) { s[k] = 0.f; s2[k] = 0.f; }
  for (int i = blockIdx.x * blockDim.x + threadIdx.x; i < Ee; i += gridDim.x * blockDim.x) {
#pragma unroll
    for (int k = 0; k < 9; ++k) {
      float v = in[i * 9 + k];
      s[k] += v; s2[k] += v * v;
    }
  }
#pragma unroll
  for (int k = 0; k < 9; ++k) {
    for (int off = 1; off < 64; off <<= 1) {
      s[k] += __shfl_xor(s[k], off);
      s2[k] += __shfl_xor(s2[k], off);
    }
  }
  if ((threadIdx.x & 63) == 0) {
#pragma unroll
    for (int k = 0; k < 9; ++k) {
      atomicAdd(&cs[k], s[k]);
      atomicAdd(&cs[16 + k], s2[k]);
    }
  }
}

// ---------------- lift: h = relu(x @ lift_W + b), stored fp16 ----------------
__global__ __launch_bounds__(256) void lift_kernel(const float* __restrict__ x,
                                                   const float* __restrict__ W,
                                                   const float* __restrict__ b,
                                                   f16* __restrict__ hq) {
  __shared__ float xs[INDIM];
  int n = blockIdx.x, ch = threadIdx.x;
  if (ch < INDIM) xs[ch] = x[n * INDIM + ch];
  __syncthreads();
  float s = b[ch];
#pragma unroll
  for (int k = 0; k < INDIM; ++k) s += xs[k] * W[k * 256 + ch];
  hq[n * 256 + ch] = (f16)fmaxf(s, 0.f);
}

// ---------------- CSR build (by destination) ----------------
__global__ __launch_bounds__(256) void degree_kernel(const int* __restrict__ dst,
                                                     int* __restrict__ deg) {
  int e = blockIdx.x * 256 + threadIdx.x;
  if (e < Ee) atomicAdd(&deg[dst[e]], 1);
}

__global__ __launch_bounds__(1024) void scan_kernel(const int* __restrict__ deg,
                                                    int* __restrict__ rowptr,
                                                    int* __restrict__ cursor) {
  __shared__ int part[1024];
  int tid = threadIdx.x;
  const int CH = (Nn + 1023) / 1024;
  int start = tid * CH;
  int s = 0;
  for (int i = 0; i < CH; ++i) { int idx = start + i; if (idx < Nn) s += deg[idx]; }
  part[tid] = s;
  __syncthreads();
  for (int off = 1; off < 1024; off <<= 1) {
    int v = part[tid];
    int w = (tid >= off) ? part[tid - off] : 0;
    __syncthreads();
    part[tid] = v + w;
    __syncthreads();
  }
  int run = part[tid] - s;  // exclusive prefix
  for (int i = 0; i < CH; ++i) {
    int idx = start + i;
    if (idx < Nn) { rowptr[idx] = run; cursor[idx] = run; run += deg[idx]; }
  }
  if (tid == 0) rowptr[Nn] = Ee;
}

__global__ __launch_bounds__(256) void fill_kernel(const int* __restrict__ dst,
                                                   int* __restrict__ cursor,
                                                   int* __restrict__ perm) {
  int e = blockIdx.x * 256 + threadIdx.x;
  if (e < Ee) {
    int pos = atomicAdd(&cursor[dst[e]], 1);
    perm[pos] = e;
  }
}

// -------- permute src/dst + normalized edge-attr into CSR order (stride 12) ------
__global__ __launch_bounds__(256) void eaperm_kernel(const float* __restrict__ edge_attr,
                                                     const float* __restrict__ cs,
                                                     const int* __restrict__ perm,
                                                     const int* __restrict__ srcIn,
                                                     const int* __restrict__ dstIn,
                                                     int* __restrict__ srcp,
                                                     int* __restrict__ dstp,
                                                     float* __restrict__ eap) {
  int idx = blockIdx.x * 256 + threadIdx.x;
  if (idx >= Ee) return;
  int e = perm[idx];
  srcp[idx] = srcIn[e];
  dstp[idx] = dstIn[e];
  const float* a = edge_attr + e * 9;
  float o[12];
#pragma unroll
  for (int k = 0; k < 9; ++k) {
    float mu = cs[k] * (1.f / Ee);
    float var = fmaxf(cs[16 + k] * (1.f / Ee) - mu * mu, 0.f);
    o[k] = (a[k] - mu) / (sqrtf(var) + 1e-8f);
  }
  o[9] = o[10] = o[11] = 0.f;
  float4 v0 = {o[0], o[1], o[2], o[3]};
  float4 v1 = {o[4], o[5], o[6], o[7]};
  float4 v2 = {o[8], o[9], o[10], o[11]};
  *(float4*)(eap + (size_t)idx * 12 + 0) = v0;
  *(float4*)(eap + (size_t)idx * 12 + 4) = v1;
  *(float4*)(eap + (size_t)idx * 12 + 8) = v2;
}

// ---------------- weight convert: fp32 [256k,256n] -> fp16 transposed ----------------
__global__ __launch_bounds__(256) void convert_kernel(const float* __restrict__ Wl,
                                                      const float* __restrict__ Wr,
                                                      const float* __restrict__ p1,
                                                      const float* __restrict__ p2,
                                                      f16* __restrict__ wt) {
  int nrow = blockIdx.x, s = blockIdx.y, k = threadIdx.x;
  const float* srcp; int n = nrow; size_t dst;
  if (s < 5) {
    dst = (size_t)s * 131072 + (size_t)nrow * 256 + k;
    if (nrow < 256) srcp = Wl + s * 65536;
    else { srcp = Wr + s * 65536; n = nrow - 256; }
  } else {
    if (nrow >= 256) return;
    dst = 655360 + (size_t)(s - 5) * 65536 + (size_t)nrow * 256 + k;
    srcp = (s == 5) ? p1 : p2;
  }
  wt[dst] = (f16)srcp[k * 256 + n];
}

__global__ __launch_bounds__(256) void prep_bias_kernel(const float* __restrict__ bl,
                                                        const float* __restrict__ br,
                                                        float* __restrict__ bc) {
  int idx = blockIdx.x * 256 + threadIdx.x;  // 2560
  if (idx >= 2560) return;
  int t = idx >> 9, c = idx & 511;
  bc[idx] = (c < 256) ? bl[t * 256 + c] : br[t * 256 + c - 256];
}

// ------------- direct-from-L2 MFMA GEMM (no LDS, no barriers) -------------
// wave = 32x32 output tile; A/B fragments loaded straight from global (L2-hot).
// grid: 4 waves/block; wid -> (mt = wid>>lgNT, nt = wid & (NT-1)), so a block's
// 4 waves share the same 32 A-rows (L1 locality). K fully unrolled -> compiler
// pipelines the 32 load+MFMA pairs with fine vmcnt.
__global__ __launch_bounds__(256) void gemm_direct(const f16* __restrict__ A,
                                                   const f16* __restrict__ BT,
                                                   const float* __restrict__ bias,
                                                   f16* __restrict__ out,
                                                   int M, int lgNT, int OS) {
  const int wid = blockIdx.x * 4 + (threadIdx.x >> 6);
  const int lane = threadIdx.x & 63;
  const int NTm1 = (1 << lgNT) - 1;
  const int mt = wid >> lgNT, nt = wid & NTm1;
  const int m0 = mt * 32, n0 = nt * 32;
  const int l15 = lane & 15, quad = lane >> 4;
  int a0r = m0 + l15;      if (a0r >= M) a0r = M - 1;
  int a1r = m0 + 16 + l15; if (a1r >= M) a1r = M - 1;
  const f16* pa0 = A + (size_t)a0r * 256 + quad * 8;
  const f16* pa1 = A + (size_t)a1r * 256 + quad * 8;
  const f16* pb0 = BT + (size_t)(n0 + l15) * 256 + quad * 8;
  const f16* pb1 = BT + (size_t)(n0 + 16 + l15) * 256 + quad * 8;
  f32x4 zero4 = {0.f, 0.f, 0.f, 0.f};
  f32x4 acc[2][2] = {{zero4, zero4}, {zero4, zero4}};
#pragma unroll
  for (int kk = 0; kk < 256; kk += 32) {
    f16x8 a0 = *(const f16x8*)(pa0 + kk);
    f16x8 a1 = *(const f16x8*)(pa1 + kk);
    f16x8 b0 = *(const f16x8*)(pb0 + kk);
    f16x8 b1 = *(const f16x8*)(pb1 + kk);
    acc[0][0] = __builtin_amdgcn_mfma_f32_16x16x32_f16(a0, b0, acc[0][0], 0, 0, 0);
    acc[0][1] = __builtin_amdgcn_mfma_f32_16x16x32_f16(a0, b1, acc[0][1], 0, 0, 0);
    acc[1][0] = __builtin_amdgcn_mfma_f32_16x16x32_f16(a1, b0, acc[1][0], 0, 0, 0);
    acc[1][1] = __builtin_amdgcn_mfma_f32_16x16x32_f16(a1, b1, acc[1][1], 0, 0, 0);
  }
  // C/D layout: col = lane&15, row = quad*4 + reg
#pragma unroll
  for (int ni = 0; ni < 2; ++ni) {
    int col = n0 + ni * 16 + l15;
    float bv = bias[col];
#pragma unroll
    for (int mi = 0; mi < 2; ++mi) {
#pragma unroll
      for (int r = 0; r < 4; ++r) {
        int row = m0 + mi * 16 + quad * 4 + r;
        if (row < M) out[(size_t)row * OS + col] = (f16)(acc[mi][ni][r] + bv);
      }
    }
  }
}

// ---------------- standalone BN apply + activation, f16 in/out ----------------
// act: 0 = ELU, 1 = ReLU
__global__ __launch_bounds__(256) void bn_apply_kernel(const f16* __restrict__ v,
                                                       const float* __restrict__ sums,
                                                       const float* __restrict__ gamma,
                                                       const float* __restrict__ beta,
                                                       f16* __restrict__ o, int act) {
  int idx = blockIdx.x * 256 + threadIdx.x;  // 1250 blocks, 8 f16 each
  size_t base = (size_t)idx * 8;
  int ch = (int)(base & 255);
  f16x8 in8 = *(const f16x8*)(v + base);
  f16x8 o8;
#pragma unroll
  for (int c = 0; c < 8; ++c) {
    float mu = sums[ch + c] * (1.f / Nn);
    float var = fmaxf(sums[256 + ch + c] * (1.f / Nn) - mu * mu, 0.f);  // biased var
    float is = rsqrtf(var + 1e-5f) * gamma[ch + c];
    float y = ((float)in8[c] - mu) * is + beta[ch + c];
    if (act == 0) y = y > 0.f ? y : (__expf(y) - 1.f);  // ELU
    else y = fmaxf(y, 0.f);                             // ReLU
    o8[c] = (f16)y;
  }
  *(f16x8*)(o + base) = o8;
}

// ---------- GATv2 phase 1: wave = 32-edge batch; lane = channel-quad ----------
__global__ __launch_bounds__(256) void logits_kernel(const f16* __restrict__ hxlr,
                                                     const float* __restrict__ eap,
                                                     const int* __restrict__ srcp,
                                                     const int* __restrict__ dstp,
                                                     const float* __restrict__ We_t,
                                                     const float* __restrict__ att_t,
                                                     float* __restrict__ zbuf) {
  const int wave = threadIdx.x >> 6, lane = threadIdx.x & 63;
  const int e0 = (blockIdx.x * 4 + wave) * 32;  // 1250 blocks * 4 waves * 32 = Ee
  const int ch = lane * 4;                      // lane owns channels [ch, ch+4)
  float we[9][4];
#pragma unroll
  for (int k = 0; k < 9; ++k) {
    float4 w4 = *(const float4*)(We_t + k * 256 + ch);
    we[k][0] = w4.x; we[k][1] = w4.y; we[k][2] = w4.z; we[k][3] = w4.w;
  }
  float4 a4 = *(const float4*)(att_t + ch);
  float att[4] = {a4.x, a4.y, a4.z, a4.w};
  const int hsel = lane >> 3;          // head this lane would store
  const bool store = (lane & 7) == 0;  // 8 storer lanes per wave
#pragma unroll 4
  for (int it = 0; it < 32; ++it) {
    int e = e0 + it;
    int j = srcp[e];  // wave-uniform
    int i = dstp[e];  // wave-uniform
    f16x4 xl4 = *(const f16x4*)(hxlr + (size_t)j * 512 + ch);        // coalesced row
    f16x4 xr4 = *(const f16x4*)(hxlr + (size_t)i * 512 + 256 + ch);  // coalesced row
    const float* ep = eap + (size_t)e * 12;  // wave-uniform
    float4 e04 = *(const float4*)ep;
    float4 e14 = *(const float4*)(ep + 4);
    float e8 = ep[8];
    float sp = 0.f;
#pragma unroll
    for (int c = 0; c < 4; ++c) {
      float v = (float)xl4[c] + (float)xr4[c];
      v += e04.x * we[0][c] + e04.y * we[1][c] + e04.z * we[2][c] + e04.w * we[3][c];
      v += e14.x * we[4][c] + e14.y * we[5][c] + e14.z * we[6][c] + e14.w * we[7][c];
      v += e8 * we[8][c];
      v = v > 0.f ? v : 0.2f * v;  // leaky_relu 0.2
      sp += att[c] * v;
    }
    sp += __shfl_xor(sp, 1);
    sp += __shfl_xor(sp, 2);
    sp += __shfl_xor(sp, 4);
    float z = __expf(fminf(sp, 75.f));
    if (store) zbuf[(size_t)hsel * Ee + e] = z;
  }
}

// ------- GATv2 phase 2: node-parallel aggregation, denom computed inline -------
__global__ __launch_bounds__(256) void agg_kernel(const f16* __restrict__ hxlr,
                                                  const float* __restrict__ zbuf,
                                                  const int* __restrict__ srcp,
                                                  const int* __restrict__ rowptr,
                                                  const float* __restrict__ cb_t,
                                                  f16* __restrict__ outb) {
  int wave = threadIdx.x >> 6, lane = threadIdx.x & 63;
  int i = blockIdx.x * 4 + wave;
  if (i >= Nn) return;
  int ch = lane * 4, h = lane >> 3;
  const float* zb = zbuf + (size_t)h * Ee;
  float acc[4] = {0.f, 0.f, 0.f, 0.f};
  float d = 0.f;
  int r0 = rowptr[i], r1 = rowptr[i + 1];
  for (int base = r0; base < r1; base += 16) {
    int cnt = r1 - base;  // >= 1
    int idxb[16];
#pragma unroll
    for (int b = 0; b < 16; ++b) idxb[b] = base + (b < cnt ? b : cnt - 1);
    float zv[16];
#pragma unroll
    for (int b = 0; b < 16; ++b) zv[b] = zb[idxb[b]];
    f16x4 xv[16];
#pragma unroll
    for (int b = 0; b < 16; ++b) {
      int j = srcp[idxb[b]];
      xv[b] = *(const f16x4*)(hxlr + (size_t)j * 512 + ch);
    }
#pragma unroll
    for (int b = 0; b < 16; ++b) {
      float zz = (b < cnt) ? zv[b] : 0.f;
      d += zz;
#pragma unroll
      for (int c = 0; c < 4; ++c) acc[c] += zz * (float)xv[b][c];
    }
  }
  float inv = 1.f / (d + 1e-16f);
  float4 cb4 = *(const float4*)(cb_t + ch);
  f16x4 o;
  o[0] = (f16)(acc[0] * inv + cb4.x);
  o[1] = (f16)(acc[1] * inv + cb4.y);
  o[2] = (f16)(acc[2] * inv + cb4.z);
  o[3] = (f16)(acc[3] * inv + cb4.w);
  *(f16x4*)(outb + (size_t)i * 256 + ch) = o;
}

// ---------------- BatchNorm batch-stats (vectorized, LDS pre-reduce) ----------------
__global__ __launch_bounds__(256) void bn_stats_kernel(const f16* __restrict__ v,
                                                       float* __restrict__ sums) {
  __shared__ float ls[512];
  int tid = threadIdx.x;
  for (int i = tid; i < 512; i += 256) ls[i] = 0.f;
  __syncthreads();
  int wave = tid >> 6, lane = tid & 63, ch = lane * 4;
  float s[4] = {0.f, 0.f, 0.f, 0.f}, s2[4] = {0.f, 0.f, 0.f, 0.f};
  for (int r = blockIdx.x * 4 + wave; r < Nn; r += gridDim.x * 4) {
    f16x4 x4 = *(const f16x4*)(v + (size_t)r * 256 + ch);
#pragma unroll
    for (int c = 0; c < 4; ++c) {
      float x = (float)x4[c];
      s[c] += x; s2[c] += x * x;
    }
  }
#pragma unroll
  for (int c = 0; c < 4; ++c) {
    atomicAdd(&ls[ch + c], s[c]);
    atomicAdd(&ls[256 + ch + c], s2[c]);
  }
  __syncthreads();
  for (int i = tid; i < 512; i += 256) atomicAdd(&sums[i], ls[i]);
}

// ---------------- final: BN(pbn2)+ReLU folded, 256 -> 3 projection ----------------
__global__ __launch_bounds__(256) void final_kernel(const f16* __restrict__ hq,
                                                    const float* __restrict__ sums,
                                                    const float* __restrict__ gamma,
                                                    const float* __restrict__ beta,
                                                    const float* __restrict__ W,
                                                    const float* __restrict__ b,
                                                    float* __restrict__ out3) {
  int wave = threadIdx.x >> 6, lane = threadIdx.x & 63;
  int n = blockIdx.x * 4 + wave;
  if (n >= Nn) return;
  int ch = lane * 4;
  float4 su = *(const float4*)(sums + ch);
  float4 sq = *(const float4*)(sums + 256 + ch);
  float4 g4 = *(const float4*)(gamma + ch);
  float4 b4 = *(const float4*)(beta + ch);
  float su_[4] = {su.x, su.y, su.z, su.w};
  float sq_[4] = {sq.x, sq.y, sq.z, sq.w};
  float g_[4] = {g4.x, g4.y, g4.z, g4.w};
  float bb_[4] = {b4.x, b4.y, b4.z, b4.w};
  f16x4 h4 = *(const f16x4*)(hq + (size_t)n * 256 + ch);
  float s0 = 0.f, s1 = 0.f, s2 = 0.f;
#pragma unroll
  for (int c = 0; c < 4; ++c) {
    float mu = su_[c] * (1.f / Nn);
    float var = fmaxf(sq_[c] * (1.f / Nn) - mu * mu, 0.f);
    float is = rsqrtf(var + 1e-5f) * g_[c];
    float y = fmaxf(((float)h4[c] - mu) * is + bb_[c], 0.f);
    const float* w = W + (ch + c) * 3;
    s0 += y * w[0]; s1 += y * w[1]; s2 += y * w[2];
  }
  for (int off = 1; off < 64; off <<= 1) {
    s0 += __shfl_xor(s0, off);
    s1 += __shfl_xor(s1, off);
    s2 += __shfl_xor(s2, off);
  }
  if (lane == 0) {
    out3[n * 3 + 0] = s0 + b[0];
    out3[n * 3 + 1] = s1 + b[1];
    out3[n * 3 + 2] = s2 + b[2];
  }
}

extern "C" void kernel_launch(void* const* d_in, const int* in_sizes, int n_in,
                              void* d_out, int out_size, void* d_ws, size_t ws_size,
                              hipStream_t stream) {
  const float* x         = (const float*)d_in[0];
  const float* edge_attr = (const float*)d_in[1];
  const int*   eidx      = (const int*)d_in[2];
  const float* lift_W    = (const float*)d_in[3];
  const float* lift_b    = (const float*)d_in[4];
  const float* Wl        = (const float*)d_in[5];
  const float* bl        = (const float*)d_in[6];
  const float* Wr        = (const float*)d_in[7];
  const float* br        = (const float*)d_in[8];
  const float* We        = (const float*)d_in[9];
  const float* att       = (const float*)d_in[10];
  const float* conv_b    = (const float*)d_in[11];
  const float* bn_g      = (const float*)d_in[12];
  const float* bn_b      = (const float*)d_in[13];
  const float* p1_W      = (const float*)d_in[14];
  const float* p1_b      = (const float*)d_in[15];
  const float* pbn1_g    = (const float*)d_in[16];
  const float* pbn1_b    = (const float*)d_in[17];
  const float* p2_W      = (const float*)d_in[18];
  const float* p2_b      = (const float*)d_in[19];
  const float* pbn2_g    = (const float*)d_in[20];
  const float* pbn2_b    = (const float*)d_in[21];
  const float* p3_W      = (const float*)d_in[22];
  const float* p3_b      = (const float*)d_in[23];
  const int* srcI = eidx;
  const int* dstI = eidx + Ee;

  char* wp = (char*)d_ws;
  auto carve = [&](size_t bytes) -> void* {
    void* p = (void*)wp;
    wp += (bytes + 255) & ~(size_t)255;
    return p;
  };
  float* eap    = (float*)carve((size_t)Ee * 12 * sizeof(float));
  f16*   h16    = (f16*)carve((size_t)Nn * 256 * sizeof(f16));  // overlaid by zbuf after gemm t=0
  f16*   w16t   = (f16*)carve((size_t)786432 * sizeof(f16));
  float* biascat= (float*)carve((size_t)2560 * sizeof(float));
  f16*   hxlr   = (f16*)carve((size_t)Nn * 512 * sizeof(f16));
  f16*   outb16 = (f16*)carve((size_t)Nn * 256 * sizeof(f16));
  f16*   happly = (f16*)carve((size_t)Nn * 256 * sizeof(f16));
  int*   deg    = (int*)carve((size_t)Nn * sizeof(int));
  int*   rowptr = (int*)carve((size_t)(Nn + 1) * sizeof(int));
  int*   cursor = (int*)carve((size_t)Nn * sizeof(int));
  int*   perm   = (int*)carve((size_t)Ee * sizeof(int));
  int*   srcp   = (int*)carve((size_t)Ee * sizeof(int));
  int*   dstp   = (int*)carve((size_t)Ee * sizeof(int));
  float* cstats = (float*)carve(32 * sizeof(float));
  float* bnsA   = (float*)carve((size_t)7 * 512 * sizeof(float));
  float* zbuf   = (float*)h16;  // Ee*8*4 = Nn*256*2 bytes; h16 dead after gemm t=0

  hipMemsetAsync(cstats, 0, 32 * sizeof(float), stream);
  hipMemsetAsync(deg, 0, Nn * sizeof(int), stream);
  hipMemsetAsync(bnsA, 0, (size_t)7 * 512 * sizeof(float), stream);

  colstats_kernel<<<64, 256, 0, stream>>>(edge_attr, cstats);
  lift_kernel<<<Nn, 256, 0, stream>>>(x, lift_W, lift_b, h16);
  degree_kernel<<<(Ee + 255) / 256, 256, 0, stream>>>(dstI, deg);
  scan_kernel<<<1, 1024, 0, stream>>>(deg, rowptr, cursor);
  fill_kernel<<<(Ee + 255) / 256, 256, 0, stream>>>(dstI, cursor, perm);
  eaperm_kernel<<<(Ee + 255) / 256, 256, 0, stream>>>(edge_attr, cstats, perm, srcI, dstI, srcp, dstp, eap);
  convert_kernel<<<dim3(512, 7), 256, 0, stream>>>(Wl, Wr, p1_W, p2_W, w16t);
  prep_bias_kernel<<<10, 256, 0, stream>>>(bl, br, biascat);

  const int MT = (Nn + 31) / 32;  // 313 m-tiles
  const int GB512 = MT * 16 / 4;  // 1252 blocks (lgNT=4)
  const int GB256 = MT * 8 / 4;   // 626 blocks  (lgNT=3)
  for (int t = 0; t < Tt; ++t) {
    const f16* Ain;
    if (t == 0) Ain = h16;
    else {
      bn_apply_kernel<<<1250, 256, 0, stream>>>(outb16, bnsA + (size_t)(t - 1) * 512,
                                                bn_g + (t - 1) * 256, bn_b + (t - 1) * 256,
                                                happly, 0);
      Ain = happly;
    }
    gemm_direct<<<GB512, 256, 0, stream>>>(Ain, w16t + (size_t)t * 131072,
                                           biascat + t * 512, hxlr, Nn, 4, 512);
    logits_kernel<<<1250, 256, 0, stream>>>(hxlr, eap, srcp, dstp,
                                            We + t * 9 * 256, att + t * 256, zbuf);
    agg_kernel<<<2500, 256, 0, stream>>>(hxlr, zbuf, srcp, rowptr,
                                         conv_b + t * 256, outb16);
    bn_stats_kernel<<<64, 256, 0, stream>>>(outb16, bnsA + (size_t)t * 512);
  }
  // projection head
  f16* pA = hxlr;                    // Nn*256
  f16* pB = hxlr + (size_t)Nn * 256; // Nn*256
  bn_apply_kernel<<<1250, 256, 0, stream>>>(outb16, bnsA + 4 * 512,
                                            bn_g + 4 * 256, bn_b + 4 * 256, happly, 0);
  gemm_direct<<<GB256, 256, 0, stream>>>(happly, w16t + 655360, p1_b, pA, Nn, 3, 256);
  bn_stats_kernel<<<64, 256, 0, stream>>>(pA, bnsA + 5 * 512);
  bn_apply_kernel<<<1250, 256, 0, stream>>>(pA, bnsA + 5 * 512, pbn1_g, pbn1_b, happly, 1);
  gemm_direct<<<GB256, 256, 0, stream>>>(happly, w16t + 720896, p2_b, pB, Nn, 3, 256);
  bn_stats_kernel<<<64, 256, 0, stream>>>(pB, bnsA + 6 * 512);
  final_kernel<<<2500, 256, 0, stream>>>(pB, bnsA + 6 * 512, pbn2_g, pbn2_b, p3_W, p3_b,
                                         (float*)d_out);
}

// Round 8
// 623.032 us; speedup vs baseline: 1.3277x; 1.3277x over previous
//
#include <hip/hip_runtime.h>

#define Nn 10000
#define Ee 160000
#define HID 256
#define EDIM 9
#define INDIM 10
#define Tt 5

typedef _Float16 f16;
typedef _Float16 f16x8 __attribute__((ext_vector_type(8)));
typedef _Float16 f16x4 __attribute__((ext_vector_type(4)));
typedef float f32x4 __attribute__((ext_vector_type(4)));

// ---------------- edge-attr column stats (mean / sumsq) ----------------
__global__ __launch_bounds__(256) void colstats_kernel(const float* __restrict__ in,
                                                       float* __restrict__ cs) {
  float s[9], s2[9];
#pragma unroll
  for (int k = 0; k < 9; ++k) { s[k] = 0.f; s2[k] = 0.f; }
  for (int i = blockIdx.x * blockDim.x + threadIdx.x; i < Ee; i += gridDim.x * blockDim.x) {
#pragma unroll
    for (int k = 0; k < 9; ++k) {
      float v = in[i * 9 + k];
      s[k] += v; s2[k] += v * v;
    }
  }
#pragma unroll
  for (int k = 0; k < 9; ++k) {
    for (int off = 1; off < 64; off <<= 1) {
      s[k] += __shfl_xor(s[k], off);
      s2[k] += __shfl_xor(s2[k], off);
    }
  }
  if ((threadIdx.x & 63) == 0) {
#pragma unroll
    for (int k = 0; k < 9; ++k) {
      atomicAdd(&cs[k], s[k]);
      atomicAdd(&cs[16 + k], s2[k]);
    }
  }
}

// ---------------- lift: h = relu(x @ lift_W + b), stored fp16 ----------------
__global__ __launch_bounds__(256) void lift_kernel(const float* __restrict__ x,
                                                   const float* __restrict__ W,
                                                   const float* __restrict__ b,
                                                   f16* __restrict__ hq) {
  __shared__ float xs[INDIM];
  int n = blockIdx.x, ch = threadIdx.x;
  if (ch < INDIM) xs[ch] = x[n * INDIM + ch];
  __syncthreads();
  float s = b[ch];
#pragma unroll
  for (int k = 0; k < INDIM; ++k) s += xs[k] * W[k * 256 + ch];
  hq[n * 256 + ch] = (f16)fmaxf(s, 0.f);
}

// ---------------- CSR build (by destination) ----------------
__global__ __launch_bounds__(256) void degree_kernel(const int* __restrict__ dst,
                                                     int* __restrict__ deg) {
  int e = blockIdx.x * 256 + threadIdx.x;
  if (e < Ee) atomicAdd(&deg[dst[e]], 1);
}

__global__ __launch_bounds__(1024) void scan_kernel(const int* __restrict__ deg,
                                                    int* __restrict__ rowptr,
                                                    int* __restrict__ cursor) {
  __shared__ int part[1024];
  int tid = threadIdx.x;
  const int CH = (Nn + 1023) / 1024;
  int start = tid * CH;
  int s = 0;
  for (int i = 0; i < CH; ++i) { int idx = start + i; if (idx < Nn) s += deg[idx]; }
  part[tid] = s;
  __syncthreads();
  for (int off = 1; off < 1024; off <<= 1) {
    int v = part[tid];
    int w = (tid >= off) ? part[tid - off] : 0;
    __syncthreads();
    part[tid] = v + w;
    __syncthreads();
  }
  int run = part[tid] - s;  // exclusive prefix
  for (int i = 0; i < CH; ++i) {
    int idx = start + i;
    if (idx < Nn) { rowptr[idx] = run; cursor[idx] = run; run += deg[idx]; }
  }
  if (tid == 0) rowptr[Nn] = Ee;
}

__global__ __launch_bounds__(256) void fill_kernel(const int* __restrict__ dst,
                                                   int* __restrict__ cursor,
                                                   int* __restrict__ perm) {
  int e = blockIdx.x * 256 + threadIdx.x;
  if (e < Ee) {
    int pos = atomicAdd(&cursor[dst[e]], 1);
    perm[pos] = e;
  }
}

// -------- permute src + normalized edge-attr into CSR order (stride 12) ------
__global__ __launch_bounds__(256) void eaperm_kernel(const float* __restrict__ edge_attr,
                                                     const float* __restrict__ cs,
                                                     const int* __restrict__ perm,
                                                     const int* __restrict__ srcIn,
                                                     int* __restrict__ srcp,
                                                     float* __restrict__ eap) {
  int idx = blockIdx.x * 256 + threadIdx.x;
  if (idx >= Ee) return;
  int e = perm[idx];
  srcp[idx] = srcIn[e];
  const float* a = edge_attr + e * 9;
  float o[12];
#pragma unroll
  for (int k = 0; k < 9; ++k) {
    float mu = cs[k] * (1.f / Ee);
    float var = fmaxf(cs[16 + k] * (1.f / Ee) - mu * mu, 0.f);
    o[k] = (a[k] - mu) / (sqrtf(var) + 1e-8f);
  }
  o[9] = o[10] = o[11] = 0.f;
  float4 v0 = {o[0], o[1], o[2], o[3]};
  float4 v1 = {o[4], o[5], o[6], o[7]};
  float4 v2 = {o[8], o[9], o[10], o[11]};
  *(float4*)(eap + (size_t)idx * 12 + 0) = v0;
  *(float4*)(eap + (size_t)idx * 12 + 4) = v1;
  *(float4*)(eap + (size_t)idx * 12 + 8) = v2;
}

// ---------------- weight convert: fp32 [256k,256n] -> fp16 transposed ----------------
__global__ __launch_bounds__(256) void convert_kernel(const float* __restrict__ Wl,
                                                      const float* __restrict__ Wr,
                                                      const float* __restrict__ p1,
                                                      const float* __restrict__ p2,
                                                      f16* __restrict__ wt) {
  int nrow = blockIdx.x, s = blockIdx.y, k = threadIdx.x;
  const float* srcp; int n = nrow; size_t dst;
  if (s < 5) {
    dst = (size_t)s * 131072 + (size_t)nrow * 256 + k;
    if (nrow < 256) srcp = Wl + s * 65536;
    else { srcp = Wr + s * 65536; n = nrow - 256; }
  } else {
    if (nrow >= 256) return;
    dst = 655360 + (size_t)(s - 5) * 65536 + (size_t)nrow * 256 + k;
    srcp = (s == 5) ? p1 : p2;
  }
  wt[dst] = (f16)srcp[k * 256 + n];
}

__global__ __launch_bounds__(256) void prep_bias_kernel(const float* __restrict__ bl,
                                                        const float* __restrict__ br,
                                                        float* __restrict__ bc) {
  int idx = blockIdx.x * 256 + threadIdx.x;  // 2560
  if (idx >= 2560) return;
  int t = idx >> 9, c = idx & 511;
  bc[idx] = (c < 256) ? bl[t * 256 + c] : br[t * 256 + c - 256];
}

// ---------------- fp16 MFMA GEMM, full-K LDS staging, folded BN+act on A ----------------
// act: -1 = none, 0 = ELU, 1 = ReLU (BN params: sums[512], gamma, beta)
__global__ __launch_bounds__(256) void gemm16_kernel(const f16* __restrict__ A,
                                                     const f16* __restrict__ BT,
                                                     const float* __restrict__ bias,
                                                     const float* __restrict__ sums,
                                                     const float* __restrict__ gamma,
                                                     const float* __restrict__ beta,
                                                     int act,
                                                     f16* __restrict__ out,
                                                     int M, int OS) {
  __shared__ __align__(16) f16 As[64][264];
  __shared__ __align__(16) f16 Bs[64][264];
  const int tid = threadIdx.x;
  const int wave = tid >> 6, lane = tid & 63;
  const int l15 = lane & 15, quad = lane >> 4;
  const int m0 = blockIdx.y * 64, n0 = blockIdx.x * 64;
  const int wm = (wave >> 1) * 32, wn = (wave & 1) * 32;
  const int colbase = (tid & 31) * 8, rowbase = tid >> 5;
  float sA[8], tA[8];
  if (act >= 0) {
#pragma unroll
    for (int c4 = 0; c4 < 2; ++c4) {
      float4 su = *(const float4*)(sums + colbase + c4 * 4);
      float4 sq = *(const float4*)(sums + 256 + colbase + c4 * 4);
      float4 g4 = *(const float4*)(gamma + colbase + c4 * 4);
      float4 b4 = *(const float4*)(beta + colbase + c4 * 4);
      float su_[4] = {su.x, su.y, su.z, su.w};
      float sq_[4] = {sq.x, sq.y, sq.z, sq.w};
      float g_[4] = {g4.x, g4.y, g4.z, g4.w};
      float b_[4] = {b4.x, b4.y, b4.z, b4.w};
#pragma unroll
      for (int c = 0; c < 4; ++c) {
        float mu = su_[c] * (1.f / Nn);
        float var = fmaxf(sq_[c] * (1.f / Nn) - mu * mu, 0.f);
        float is = rsqrtf(var + 1e-5f) * g_[c];
        sA[c4 * 4 + c] = is;
        tA[c4 * 4 + c] = b_[c] - mu * is;
      }
    }
  }
#pragma unroll
  for (int i = 0; i < 8; ++i) {
    int row = rowbase + 8 * i;
    f16x8 av = {};
    int gm = m0 + row;
    if (gm < M) av = *(const f16x8*)(A + (size_t)gm * 256 + colbase);
    if (act >= 0) {
#pragma unroll
      for (int e = 0; e < 8; ++e) {
        float y = (float)av[e] * sA[e] + tA[e];
        if (act == 0) y = y > 0.f ? y : (__expf(y) - 1.f);
        else y = fmaxf(y, 0.f);
        av[e] = (f16)y;
      }
    }
    *(f16x8*)(&As[row][colbase]) = av;
    f16x8 bv = *(const f16x8*)(BT + (size_t)(n0 + row) * 256 + colbase);
    *(f16x8*)(&Bs[row][colbase]) = bv;
  }
  __syncthreads();
  f32x4 zero4 = {0.f, 0.f, 0.f, 0.f};
  f32x4 acc[2][2] = {{zero4, zero4}, {zero4, zero4}};
#pragma unroll
  for (int kk = 0; kk < 256; kk += 32) {
    f16x8 a0 = *(const f16x8*)(&As[wm + l15][kk + quad * 8]);
    f16x8 a1 = *(const f16x8*)(&As[wm + 16 + l15][kk + quad * 8]);
    f16x8 b0 = *(const f16x8*)(&Bs[wn + l15][kk + quad * 8]);
    f16x8 b1 = *(const f16x8*)(&Bs[wn + 16 + l15][kk + quad * 8]);
    acc[0][0] = __builtin_amdgcn_mfma_f32_16x16x32_f16(a0, b0, acc[0][0], 0, 0, 0);
    acc[0][1] = __builtin_amdgcn_mfma_f32_16x16x32_f16(a0, b1, acc[0][1], 0, 0, 0);
    acc[1][0] = __builtin_amdgcn_mfma_f32_16x16x32_f16(a1, b0, acc[1][0], 0, 0, 0);
    acc[1][1] = __builtin_amdgcn_mfma_f32_16x16x32_f16(a1, b1, acc[1][1], 0, 0, 0);
  }
  // epilogue: bias add, fp16 via LDS transpose for coalesced 16B stores
  __syncthreads();
  f16* Cs = (f16*)&As[0][0];  // 64 x 72 tile
#pragma unroll
  for (int ni = 0; ni < 2; ++ni) {
    int nl = wn + ni * 16 + l15;
    float bv = bias[n0 + nl];
#pragma unroll
    for (int mi = 0; mi < 2; ++mi)
#pragma unroll
      for (int r = 0; r < 4; ++r)
        Cs[(wm + mi * 16 + quad * 4 + r) * 72 + nl] = (f16)(acc[mi][ni][r] + bv);
  }
  __syncthreads();
  {
    int row = tid >> 2, c4 = (tid & 3) * 16;
    int gm = m0 + row;
    if (gm < M) {
      f16x8 v0 = *(const f16x8*)(&Cs[row * 72 + c4]);
      f16x8 v1 = *(const f16x8*)(&Cs[row * 72 + c4 + 8]);
      *(f16x8*)(out + (size_t)gm * OS + n0 + c4) = v0;
      *(f16x8*)(out + (size_t)gm * OS + n0 + c4 + 8) = v1;
    }
  }
}

// ---------- Fused GATv2 edge+softmax+aggregate: wave/node, NO online max ----------
// z = exp(min(logit,75)) directly (validated R3-R7) -> loop-carried dep is only
// d += z and 4 acc FMAs. Batch-4 edges: 8+ independent loads in flight.
// Single xl gather serves both logit and aggregation (halves gather traffic
// vs split logits/agg kernels; no zbuf round-trip).
__global__ __launch_bounds__(256) void gat_fused(const f16* __restrict__ hxlr,
                                                 const float* __restrict__ eap,
                                                 const int* __restrict__ srcp,
                                                 const int* __restrict__ rowptr,
                                                 const float* __restrict__ We_t,
                                                 const float* __restrict__ att_t,
                                                 const float* __restrict__ cb_t,
                                                 f16* __restrict__ outb) {
  int wave = threadIdx.x >> 6, lane = threadIdx.x & 63;
  int i = blockIdx.x * 4 + wave;
  if (i >= Nn) return;
  int ch = lane * 4;  // lane owns flat channels [ch, ch+4); head = lane>>3
  float we[9][4];
#pragma unroll
  for (int k = 0; k < 9; ++k) {
    float4 w4 = *(const float4*)(We_t + k * 256 + ch);
    we[k][0] = w4.x; we[k][1] = w4.y; we[k][2] = w4.z; we[k][3] = w4.w;
  }
  float4 a4 = *(const float4*)(att_t + ch);
  float att[4] = {a4.x, a4.y, a4.z, a4.w};
  f16x4 xr4 = *(const f16x4*)(hxlr + (size_t)i * 512 + 256 + ch);
  float xri[4] = {(float)xr4[0], (float)xr4[1], (float)xr4[2], (float)xr4[3]};
  float acc[4] = {0.f, 0.f, 0.f, 0.f};
  float d = 0.f;
  int r0 = rowptr[i], r1 = rowptr[i + 1];
  for (int base = r0; base < r1; base += 4) {
    int cnt = r1 - base;  // >= 1
    int ib[4];
#pragma unroll
    for (int b = 0; b < 4; ++b) ib[b] = base + (b < cnt ? b : cnt - 1);
    int js[4];
#pragma unroll
    for (int b = 0; b < 4; ++b) js[b] = srcp[ib[b]];
    float xlv[4][4];
#pragma unroll
    for (int b = 0; b < 4; ++b) {
      f16x4 v4 = *(const f16x4*)(hxlr + (size_t)js[b] * 512 + ch);
      xlv[b][0] = (float)v4[0]; xlv[b][1] = (float)v4[1];
      xlv[b][2] = (float)v4[2]; xlv[b][3] = (float)v4[3];
    }
    float sp[4];
#pragma unroll
    for (int b = 0; b < 4; ++b) {
      const float* ep = eap + (size_t)ib[b] * 12;
      float4 e0 = *(const float4*)ep;
      float4 e1 = *(const float4*)(ep + 4);
      float e8 = ep[8];
      float s = 0.f;
#pragma unroll
      for (int c = 0; c < 4; ++c) {
        float v = xlv[b][c] + xri[c];
        v += e0.x * we[0][c] + e0.y * we[1][c] + e0.z * we[2][c] + e0.w * we[3][c];
        v += e1.x * we[4][c] + e1.y * we[5][c] + e1.z * we[6][c] + e1.w * we[7][c];
        v += e8 * we[8][c];
        v = v > 0.f ? v : 0.2f * v;  // leaky_relu 0.2
        s += att[c] * v;
      }
      sp[b] = s;
    }
#pragma unroll
    for (int b = 0; b < 4; ++b) {
      sp[b] += __shfl_xor(sp[b], 1);
      sp[b] += __shfl_xor(sp[b], 2);
      sp[b] += __shfl_xor(sp[b], 4);
    }
#pragma unroll
    for (int b = 0; b < 4; ++b) {
      float z = (b < cnt) ? __expf(fminf(sp[b], 75.f)) : 0.f;
      d += z;
#pragma unroll
      for (int c = 0; c < 4; ++c) acc[c] += z * xlv[b][c];
    }
  }
  float inv = 1.f / (d + 1e-16f);  // empty node -> bias only (matches ref)
  float4 cb4 = *(const float4*)(cb_t + ch);
  f16x4 o;
  o[0] = (f16)(acc[0] * inv + cb4.x);
  o[1] = (f16)(acc[1] * inv + cb4.y);
  o[2] = (f16)(acc[2] * inv + cb4.z);
  o[3] = (f16)(acc[3] * inv + cb4.w);
  *(f16x4*)(outb + (size_t)i * 256 + ch) = o;
}

// ---------------- BatchNorm batch-stats (vectorized, LDS pre-reduce) ----------------
__global__ __launch_bounds__(256) void bn_stats_kernel(const f16* __restrict__ v,
                                                       float* __restrict__ sums) {
  __shared__ float ls[512];
  int tid = threadIdx.x;
  for (int i = tid; i < 512; i += 256) ls[i] = 0.f;
  __syncthreads();
  int wave = tid >> 6, lane = tid & 63, ch = lane * 4;
  float s[4] = {0.f, 0.f, 0.f, 0.f}, s2[4] = {0.f, 0.f, 0.f, 0.f};
  for (int r = blockIdx.x * 4 + wave; r < Nn; r += gridDim.x * 4) {
    f16x4 x4 = *(const f16x4*)(v + (size_t)r * 256 + ch);
#pragma unroll
    for (int c = 0; c < 4; ++c) {
      float x = (float)x4[c];
      s[c] += x; s2[c] += x * x;
    }
  }
#pragma unroll
  for (int c = 0; c < 4; ++c) {
    atomicAdd(&ls[ch + c], s[c]);
    atomicAdd(&ls[256 + ch + c], s2[c]);
  }
  __syncthreads();
  for (int i = tid; i < 512; i += 256) atomicAdd(&sums[i], ls[i]);
}

// ---------------- final: BN(pbn2)+ReLU folded, 256 -> 3 projection ----------------
__global__ __launch_bounds__(256) void final_kernel(const f16* __restrict__ hq,
                                                    const float* __restrict__ sums,
                                                    const float* __restrict__ gamma,
                                                    const float* __restrict__ beta,
                                                    const float* __restrict__ W,
                                                    const float* __restrict__ b,
                                                    float* __restrict__ out3) {
  int wave = threadIdx.x >> 6, lane = threadIdx.x & 63;
  int n = blockIdx.x * 4 + wave;
  if (n >= Nn) return;
  int ch = lane * 4;
  float4 su = *(const float4*)(sums + ch);
  float4 sq = *(const float4*)(sums + 256 + ch);
  float4 g4 = *(const float4*)(gamma + ch);
  float4 b4 = *(const float4*)(beta + ch);
  float su_[4] = {su.x, su.y, su.z, su.w};
  float sq_[4] = {sq.x, sq.y, sq.z, sq.w};
  float g_[4] = {g4.x, g4.y, g4.z, g4.w};
  float bb_[4] = {b4.x, b4.y, b4.z, b4.w};
  f16x4 h4 = *(const f16x4*)(hq + (size_t)n * 256 + ch);
  float s0 = 0.f, s1 = 0.f, s2 = 0.f;
#pragma unroll
  for (int c = 0; c < 4; ++c) {
    float mu = su_[c] * (1.f / Nn);
    float var = fmaxf(sq_[c] * (1.f / Nn) - mu * mu, 0.f);
    float is = rsqrtf(var + 1e-5f) * g_[c];
    float y = fmaxf(((float)h4[c] - mu) * is + bb_[c], 0.f);
    const float* w = W + (ch + c) * 3;
    s0 += y * w[0]; s1 += y * w[1]; s2 += y * w[2];
  }
  for (int off = 1; off < 64; off <<= 1) {
    s0 += __shfl_xor(s0, off);
    s1 += __shfl_xor(s1, off);
    s2 += __shfl_xor(s2, off);
  }
  if (lane == 0) {
    out3[n * 3 + 0] = s0 + b[0];
    out3[n * 3 + 1] = s1 + b[1];
    out3[n * 3 + 2] = s2 + b[2];
  }
}

extern "C" void kernel_launch(void* const* d_in, const int* in_sizes, int n_in,
                              void* d_out, int out_size, void* d_ws, size_t ws_size,
                              hipStream_t stream) {
  const float* x         = (const float*)d_in[0];
  const float* edge_attr = (const float*)d_in[1];
  const int*   eidx      = (const int*)d_in[2];
  const float* lift_W    = (const float*)d_in[3];
  const float* lift_b    = (const float*)d_in[4];
  const float* Wl        = (const float*)d_in[5];
  const float* bl        = (const float*)d_in[6];
  const float* Wr        = (const float*)d_in[7];
  const float* br        = (const float*)d_in[8];
  const float* We        = (const float*)d_in[9];
  const float* att       = (const float*)d_in[10];
  const float* conv_b    = (const float*)d_in[11];
  const float* bn_g      = (const float*)d_in[12];
  const float* bn_b      = (const float*)d_in[13];
  const float* p1_W      = (const float*)d_in[14];
  const float* p1_b      = (const float*)d_in[15];
  const float* pbn1_g    = (const float*)d_in[16];
  const float* pbn1_b    = (const float*)d_in[17];
  const float* p2_W      = (const float*)d_in[18];
  const float* p2_b      = (const float*)d_in[19];
  const float* pbn2_g    = (const float*)d_in[20];
  const float* pbn2_b    = (const float*)d_in[21];
  const float* p3_W      = (const float*)d_in[22];
  const float* p3_b      = (const float*)d_in[23];
  const int* srcI = eidx;
  const int* dstI = eidx + Ee;

  char* wp = (char*)d_ws;
  auto carve = [&](size_t bytes) -> void* {
    void* p = (void*)wp;
    wp += (bytes + 255) & ~(size_t)255;
    return p;
  };
  float* eap    = (float*)carve((size_t)Ee * 12 * sizeof(float));
  f16*   h16    = (f16*)carve((size_t)Nn * 256 * sizeof(f16));
  f16*   w16t   = (f16*)carve((size_t)786432 * sizeof(f16));
  float* biascat= (float*)carve((size_t)2560 * sizeof(float));
  f16*   hxlr   = (f16*)carve((size_t)Nn * 512 * sizeof(f16));
  f16*   outb16 = (f16*)carve((size_t)Nn * 256 * sizeof(f16));
  int*   deg    = (int*)carve((size_t)Nn * sizeof(int));
  int*   rowptr = (int*)carve((size_t)(Nn + 1) * sizeof(int));
  int*   cursor = (int*)carve((size_t)Nn * sizeof(int));
  int*   perm   = (int*)carve((size_t)Ee * sizeof(int));
  int*   srcp   = (int*)carve((size_t)Ee * sizeof(int));
  float* cstats = (float*)carve(32 * sizeof(float));
  float* bnsA   = (float*)carve((size_t)7 * 512 * sizeof(float));

  hipMemsetAsync(cstats, 0, 32 * sizeof(float), stream);
  hipMemsetAsync(deg, 0, Nn * sizeof(int), stream);
  hipMemsetAsync(bnsA, 0, (size_t)7 * 512 * sizeof(float), stream);

  colstats_kernel<<<64, 256, 0, stream>>>(edge_attr, cstats);
  lift_kernel<<<Nn, 256, 0, stream>>>(x, lift_W, lift_b, h16);
  degree_kernel<<<(Ee + 255) / 256, 256, 0, stream>>>(dstI, deg);
  scan_kernel<<<1, 1024, 0, stream>>>(deg, rowptr, cursor);
  fill_kernel<<<(Ee + 255) / 256, 256, 0, stream>>>(dstI, cursor, perm);
  eaperm_kernel<<<(Ee + 255) / 256, 256, 0, stream>>>(edge_attr, cstats, perm, srcI, srcp, eap);
  convert_kernel<<<dim3(512, 7), 256, 0, stream>>>(Wl, Wr, p1_W, p2_W, w16t);
  prep_bias_kernel<<<10, 256, 0, stream>>>(bl, br, biascat);

  const int MB = (Nn + 63) / 64;  // 157
  for (int t = 0; t < Tt; ++t) {
    const f16* Ain = (t == 0) ? h16 : outb16;
    const float* sums = (t == 0) ? nullptr : bnsA + (size_t)(t - 1) * 512;
    int act = (t == 0) ? -1 : 0;
    gemm16_kernel<<<dim3(8, MB), 256, 0, stream>>>(Ain, w16t + (size_t)t * 131072,
                                                   biascat + t * 512, sums,
                                                   bn_g + (t > 0 ? (t - 1) * 256 : 0),
                                                   bn_b + (t > 0 ? (t - 1) * 256 : 0),
                                                   act, hxlr, Nn, 512);
    gat_fused<<<2500, 256, 0, stream>>>(hxlr, eap, srcp, rowptr,
                                        We + t * 9 * 256, att + t * 256,
                                        conv_b + t * 256, outb16);
    bn_stats_kernel<<<128, 256, 0, stream>>>(outb16, bnsA + (size_t)t * 512);
  }
  // projection head: p1 (BN4+ELU folded), p2 (pbn1+ReLU folded), final (pbn2+ReLU folded)
  f16* pA = hxlr;                    // Nn*256
  f16* pB = hxlr + (size_t)Nn * 256; // Nn*256
  gemm16_kernel<<<dim3(4, MB), 256, 0, stream>>>(outb16, w16t + 655360, p1_b,
                                                 bnsA + 4 * 512, bn_g + 4 * 256, bn_b + 4 * 256,
                                                 0, pA, Nn, 256);
  bn_stats_kernel<<<128, 256, 0, stream>>>(pA, bnsA + 5 * 512);
  gemm16_kernel<<<dim3(4, MB), 256, 0, stream>>>(pA, w16t + 720896, p2_b,
                                                 bnsA + 5 * 512, pbn1_g, pbn1_b,
                                                 1, pB, Nn, 256);
  bn_stats_kernel<<<128, 256, 0, stream>>>(pB, bnsA + 6 * 512);
  final_kernel<<<2500, 256, 0, stream>>>(pB, bnsA + 6 * 512, pbn2_g, pbn2_b, p3_W, p3_b,
                                         (float*)d_out);
}